// Round 1
// baseline (337.392 us; speedup 1.0000x reference)
//
#include <hip/hip_runtime.h>

#define Bsz 2
#define Tsz 2048
#define Dsz 1024
#define NHsz 16
#define Msz (Bsz*Tsz)  // 4096 rows total

typedef unsigned short bfu;  // bf16 bit pattern
typedef __attribute__((ext_vector_type(8))) short short8;   // MFMA A/B frag: 8 bf16
typedef __attribute__((ext_vector_type(4))) short short4v;
typedef __attribute__((ext_vector_type(4))) float floatx4;  // MFMA C/D frag

__device__ __forceinline__ bfu f2bf(float f) {
  // round-to-nearest-even fp32 -> bf16 (finite inputs only)
  unsigned int u = __builtin_bit_cast(unsigned int, f);
  u += 0x7fffu + ((u >> 16) & 1u);
  return (bfu)(u >> 16);
}

__device__ __forceinline__ void async16(const void* g, void* l) {
  // global -> LDS direct copy, 16B per lane; lds dest must be wave-uniform
  void* gnc = (void*)g;
  __builtin_amdgcn_global_load_lds((__attribute__((address_space(1))) void*)gnc,
                                   (__attribute__((address_space(3))) void*)l,
                                   16, 0, 0);
}

// ---------------- x: fp32 -> bf16 ----------------
__global__ __launch_bounds__(256) void convert_x(const float* __restrict__ x,
                                                 bfu* __restrict__ xb) {
  int i = blockIdx.x * 256 + threadIdx.x;           // 4 elems per thread
  float4 v = ((const float4*)x)[i];
  short4v o;
  o[0] = (short)f2bf(v.x); o[1] = (short)f2bf(v.y);
  o[2] = (short)f2bf(v.z); o[3] = (short)f2bf(v.w);
  *(short4v*)(xb + (size_t)i * 4) = o;
}

// ---------------- W (KxN fp32, 1024x1024) -> WT (NxK bf16), z = 4 weights ----------------
__global__ __launch_bounds__(256) void transpose_w(const float* __restrict__ W0, const float* __restrict__ W1,
                                                   const float* __restrict__ W2, const float* __restrict__ W3,
                                                   bfu* __restrict__ wt) {
  __shared__ float tile[32][33];
  const float* W = blockIdx.z == 0 ? W0 : blockIdx.z == 1 ? W1 : blockIdx.z == 2 ? W2 : W3;
  bfu* WT = wt + (size_t)blockIdx.z * Dsz * Dsz;
  int tx = threadIdx.x, ty = threadIdx.y;           // 32 x 8
  int kb = blockIdx.y * 32, nb = blockIdx.x * 32;
#pragma unroll
  for (int i = 0; i < 4; ++i)
    tile[ty + i*8][tx] = W[(size_t)(kb + ty + i*8) * Dsz + nb + tx];
  __syncthreads();
#pragma unroll
  for (int i = 0; i < 4; ++i)
    WT[(size_t)(nb + ty + i*8) * Dsz + kb + tx] = f2bf(tile[tx][ty + i*8]);
}

// ---------------- 128x128 bf16 MFMA GEMM: C = A(MxK) * BT(NxK)^T ----------------
// grid: (N/128, M/128, Z). scale0 applied to z==0 output (Q scaling).
template <bool F32OUT>
__global__ __launch_bounds__(256) void gemm128(const bfu* __restrict__ A, const bfu* __restrict__ Bt0,
                                               void* __restrict__ C0, int K, int N,
                                               size_t strideB, size_t strideC, float scale0) {
  const int tid = threadIdx.x, wave = tid >> 6, lane = tid & 63;
  const int g = lane >> 4, c = lane & 15;
  const int m0 = blockIdx.y * 128, n0 = blockIdx.x * 128;
  const bfu* Bt = Bt0 + strideB * blockIdx.z;
  const float scale = (blockIdx.z == 0) ? scale0 : 1.0f;
  __shared__ bfu As[128 * 32];   // [row][k] row-major
  __shared__ bfu Bs[128 * 32];   // [n]][k] row-major (from W^T)
  floatx4 acc[4][4] = {};
  const int srow = lane >> 2, scol = (lane & 3) * 8;   // staging: 16 rows x 32 cols per 1KB chunk
  const bfu* gA = A  + (size_t)(m0 + srow) * K + scol;
  const bfu* gB = Bt + (size_t)(n0 + srow) * K + scol;
  const int wm = (wave >> 1) * 64, wn = (wave & 1) * 64;
  for (int k0 = 0; k0 < K; k0 += 32) {
    __syncthreads();               // prior reads done before overwrite
#pragma unroll
    for (int cc = 0; cc < 2; ++cc) {
      const int chunk = wave * 2 + cc;               // 8 chunks of 1KB each
      async16(gA + (size_t)chunk * 16 * K + k0, &As[chunk * 512]);
      async16(gB + (size_t)chunk * 16 * K + k0, &Bs[chunk * 512]);
    }
    __syncthreads();               // compiler drains vmcnt before barrier
    short8 afr[4], bfr[4];
#pragma unroll
    for (int t = 0; t < 4; ++t) afr[t] = *(const short8*)&As[(wm + t*16 + c) * 32 + g * 8];
#pragma unroll
    for (int t = 0; t < 4; ++t) bfr[t] = *(const short8*)&Bs[(wn + t*16 + c) * 32 + g * 8];
#pragma unroll
    for (int i = 0; i < 4; ++i)
#pragma unroll
      for (int j = 0; j < 4; ++j)
        acc[i][j] = __builtin_amdgcn_mfma_f32_16x16x32_bf16(afr[i], bfr[j], acc[i][j], 0, 0, 0);
  }
#pragma unroll
  for (int i = 0; i < 4; ++i) {
#pragma unroll
    for (int j = 0; j < 4; ++j) {
      const int m = m0 + wm + i*16 + g*4;
      const int n = n0 + wn + j*16 + c;
#pragma unroll
      for (int r = 0; r < 4; ++r) {
        float v = acc[i][j][r] * scale;
        if (F32OUT) ((float*)C0)[(size_t)(m + r) * N + n] = v;
        else        ((bfu*)C0)[strideC * blockIdx.z + (size_t)(m + r) * N + n] = f2bf(v);
      }
    }
  }
}

// ---------------- causal flash attention ----------------
// qkv: 3 x (Msz x 1024) bf16, row = b*T + t, col = h*64 + d. Q pre-scaled by 1/8.
// grid: (T/128, B*NH). block 256 = 4 waves; wave w owns q rows [q0+32w, q0+32w+31].
__global__ __launch_bounds__(256) void attn_kernel(const bfu* __restrict__ qkv,
                                                   bfu* __restrict__ obuf) {
  const int tid = threadIdx.x, wave = tid >> 6, lane = tid & 63;
  const int g = lane >> 4, c = lane & 15;
  const int b = blockIdx.y >> 4, h = blockIdx.y & 15;
  const int q0 = blockIdx.x * 128;
  const size_t base = (size_t)b * Tsz * Dsz + h * 64;
  const bfu* Qp = qkv + base;
  const bfu* Kp = qkv + (size_t)Msz * Dsz + base;
  const bfu* Vp = qkv + (size_t)2 * Msz * Dsz + base;

  __shared__ bfu Ks[32 * 72];       // K tile [key][d], stride 72 (conflict-free b128 reads)
  __shared__ bfu Vts[64 * 32];      // V^T tile [d][key], key-block XOR swizzle
  __shared__ bfu Ps[4][32 * 40];    // per-wave P tile [row][key], stride 40

  const int qw = q0 + wave * 32;
  short8 aq[2][2];                  // Q fragments: [tm][kk]
#pragma unroll
  for (int tm = 0; tm < 2; ++tm)
#pragma unroll
    for (int kk = 0; kk < 2; ++kk)
      aq[tm][kk] = *(const short8*)(Qp + (size_t)(qw + tm*16 + c) * Dsz + kk*32 + g*8);

  floatx4 acc[2][4] = {};           // O accum: [tm][nd], rows g*4+r, col nd*16+c
  float mi[2][4], li[2][4];
#pragma unroll
  for (int tm = 0; tm < 2; ++tm)
#pragma unroll
    for (int r = 0; r < 4; ++r) { mi[tm][r] = -3.0e38f; li[tm][r] = 0.0f; }

  const int diag = q0 / 32 + wave;       // this wave's diagonal key-tile
  const int ktmax = q0 / 32 + 3;         // last tile any wave in block needs
  const int skey = tid >> 3, sd = (tid & 7) * 8;     // staging coords
  const int kswz = skey ^ (sd & 24);                 // key ^ ((d>>3)&3)*8

  for (int kt = 0; kt <= ktmax; ++kt) {
    __syncthreads();
    {  // stage K (padded) and V^T (swizzled) tiles, cooperative
      short8 kv = *(const short8*)(Kp + (size_t)(kt*32 + skey) * Dsz + sd);
      *(short8*)&Ks[skey * 72 + sd] = kv;
      short8 vv = *(const short8*)(Vp + (size_t)(kt*32 + skey) * Dsz + sd);
#pragma unroll
      for (int i2 = 0; i2 < 8; ++i2) Vts[(sd + i2) * 32 + kswz] = (bfu)vv[i2];
    }
    __syncthreads();
    if (kt > diag) continue;           // all waves still hit both barriers each iter

    // S = Q * K^T   (Q pre-scaled by 1/sqrt(DH))
    short8 bk[2][2];
#pragma unroll
    for (int nk = 0; nk < 2; ++nk)
#pragma unroll
      for (int kk = 0; kk < 2; ++kk)
        bk[nk][kk] = *(const short8*)&Ks[(nk*16 + c) * 72 + kk*32 + g*8];
    floatx4 S[2][2] = {};
#pragma unroll
    for (int tm = 0; tm < 2; ++tm)
#pragma unroll
      for (int nk = 0; nk < 2; ++nk)
#pragma unroll
        for (int kk = 0; kk < 2; ++kk)
          S[tm][nk] = __builtin_amdgcn_mfma_f32_16x16x32_bf16(aq[tm][kk], bk[nk][kk], S[tm][nk], 0, 0, 0);

    if (kt == diag) {                  // causal mask only on diagonal tile
#pragma unroll
      for (int tm = 0; tm < 2; ++tm)
#pragma unroll
        for (int nk = 0; nk < 2; ++nk) {
          const int kpos = kt*32 + nk*16 + c;
#pragma unroll
          for (int r = 0; r < 4; ++r) {
            const int qpos = qw + tm*16 + g*4 + r;
            if (kpos > qpos) S[tm][nk][r] = -3.0e38f;
          }
        }
    }

    // online softmax (fp32), P written to per-wave LDS as bf16
#pragma unroll
    for (int tm = 0; tm < 2; ++tm) {
      float rmax[4], p0[4], p1[4], rsum[4], al[4];
#pragma unroll
      for (int r = 0; r < 4; ++r) rmax[r] = fmaxf(S[tm][0][r], S[tm][1][r]);
#pragma unroll
      for (int off = 1; off < 16; off <<= 1)
#pragma unroll
        for (int r = 0; r < 4; ++r) rmax[r] = fmaxf(rmax[r], __shfl_xor(rmax[r], off));
#pragma unroll
      for (int r = 0; r < 4; ++r) {
        const float mn = fmaxf(mi[tm][r], rmax[r]);
        al[r] = __expf(mi[tm][r] - mn);
        mi[tm][r] = mn;
        p0[r] = __expf(S[tm][0][r] - mn);
        p1[r] = __expf(S[tm][1][r] - mn);
        rsum[r] = p0[r] + p1[r];
      }
#pragma unroll
      for (int off = 1; off < 16; off <<= 1)
#pragma unroll
        for (int r = 0; r < 4; ++r) rsum[r] += __shfl_xor(rsum[r], off);
#pragma unroll
      for (int r = 0; r < 4; ++r) li[tm][r] = li[tm][r] * al[r] + rsum[r];
#pragma unroll
      for (int nd = 0; nd < 4; ++nd)
#pragma unroll
        for (int r = 0; r < 4; ++r) acc[tm][nd][r] *= al[r];
#pragma unroll
      for (int r = 0; r < 4; ++r) {
        const int prow = tm*16 + g*4 + r;
        Ps[wave][prow * 40 + c]      = f2bf(p0[r]);
        Ps[wave][prow * 40 + 16 + c] = f2bf(p1[r]);
      }
    }

    // O += P * V  (P via LDS round trip into A-layout, V^T swizzled reads)
    short8 bv[4];
#pragma unroll
    for (int nd = 0; nd < 4; ++nd) {
      const int d = nd*16 + c;
      const int kb = g ^ ((d >> 3) & 3);
      bv[nd] = *(const short8*)&Vts[d * 32 + kb * 8];
    }
#pragma unroll
    for (int tm = 0; tm < 2; ++tm) {
      const short8 ap = *(const short8*)&Ps[wave][(tm*16 + c) * 40 + g * 8];
#pragma unroll
      for (int nd = 0; nd < 4; ++nd)
        acc[tm][nd] = __builtin_amdgcn_mfma_f32_16x16x32_bf16(ap, bv[nd], acc[tm][nd], 0, 0, 0);
    }
  }

  // epilogue: O / l -> bf16 merged-heads buffer
#pragma unroll
  for (int tm = 0; tm < 2; ++tm)
#pragma unroll
    for (int nd = 0; nd < 4; ++nd)
#pragma unroll
      for (int r = 0; r < 4; ++r) {
        const int t = qw + tm*16 + g*4 + r;
        const float o = acc[tm][nd][r] / li[tm][r];
        obuf[(size_t)(b * Tsz + t) * Dsz + h * 64 + nd*16 + c] = f2bf(o);
      }
}

extern "C" void kernel_launch(void* const* d_in, const int* in_sizes, int n_in,
                              void* d_out, int out_size, void* d_ws, size_t ws_size,
                              hipStream_t stream) {
  const float* x  = (const float*)d_in[0];
  const float* Wq = (const float*)d_in[1];
  const float* Wk = (const float*)d_in[2];
  const float* Wv = (const float*)d_in[3];
  const float* Wo = (const float*)d_in[4];
  float* out = (float*)d_out;

  // workspace layout (bf16 elems): xb 4M | wt 4x1M | qkv 3x4M | obuf 4M  = 48 MiB
  bfu* xb   = (bfu*)d_ws;
  bfu* wt   = xb  + (size_t)Msz * Dsz;
  bfu* qkv  = wt  + (size_t)4 * Dsz * Dsz;
  bfu* obuf = qkv + (size_t)3 * Msz * Dsz;

  convert_x<<<dim3(Msz * Dsz / (256 * 4)), dim3(256), 0, stream>>>(x, xb);
  transpose_w<<<dim3(32, 32, 4), dim3(32, 8), 0, stream>>>(Wq, Wk, Wv, Wo, wt);
  // QKV projections; 1/sqrt(64) folded into Q (z==0)
  gemm128<false><<<dim3(Dsz / 128, Msz / 128, 3), dim3(256), 0, stream>>>(
      xb, wt, (void*)qkv, Dsz, Dsz, (size_t)Dsz * Dsz, (size_t)Msz * Dsz, 0.125f);
  attn_kernel<<<dim3(Tsz / 128, Bsz * NHsz), dim3(256), 0, stream>>>(qkv, obuf);
  // output projection -> fp32 d_out
  gemm128<true><<<dim3(Dsz / 128, Msz / 128, 1), dim3(256), 0, stream>>>(
      obuf, wt + (size_t)3 * Dsz * Dsz, (void*)out, Dsz, Dsz, (size_t)0, (size_t)0, 1.0f);
}

// Round 2
// 206.449 us; speedup vs baseline: 1.6343x; 1.6343x over previous
//
#include <hip/hip_runtime.h>

#define Bsz 2
#define Tsz 2048
#define Dsz 1024
#define NHsz 16
#define Msz (Bsz*Tsz)  // 4096 rows total

typedef unsigned short bfu;  // bf16 bit pattern
typedef __attribute__((ext_vector_type(8))) short short8;   // MFMA A/B frag: 8 bf16
typedef __attribute__((ext_vector_type(4))) short short4v;
typedef __attribute__((ext_vector_type(4))) float floatx4;  // MFMA C/D frag

__device__ __forceinline__ bfu f2bf(float f) {
  unsigned int u = __builtin_bit_cast(unsigned int, f);
  u += 0x7fffu + ((u >> 16) & 1u);
  return (bfu)(u >> 16);
}

__device__ __forceinline__ void async16(const void* g, void* l) {
  void* gnc = (void*)g;
  __builtin_amdgcn_global_load_lds((__attribute__((address_space(1))) void*)gnc,
                                   (__attribute__((address_space(3))) void*)l,
                                   16, 0, 0);
}

// ---------------- x: fp32 -> bf16 ----------------
__global__ __launch_bounds__(256) void convert_x(const float* __restrict__ x,
                                                 bfu* __restrict__ xb) {
  int i = blockIdx.x * 256 + threadIdx.x;
  float4 v = ((const float4*)x)[i];
  short4v o;
  o[0] = (short)f2bf(v.x); o[1] = (short)f2bf(v.y);
  o[2] = (short)f2bf(v.z); o[3] = (short)f2bf(v.w);
  *(short4v*)(xb + (size_t)i * 4) = o;
}

// ---------------- W (KxN fp32) -> WT (NxK bf16), z = 4 weights ----------------
__global__ __launch_bounds__(256) void transpose_w(const float* __restrict__ W0, const float* __restrict__ W1,
                                                   const float* __restrict__ W2, const float* __restrict__ W3,
                                                   bfu* __restrict__ wt) {
  __shared__ float tile[32][33];
  const float* W = blockIdx.z == 0 ? W0 : blockIdx.z == 1 ? W1 : blockIdx.z == 2 ? W2 : W3;
  bfu* WT = wt + (size_t)blockIdx.z * Dsz * Dsz;
  int tx = threadIdx.x, ty = threadIdx.y;           // 32 x 8
  int kb = blockIdx.y * 32, nb = blockIdx.x * 32;
#pragma unroll
  for (int i = 0; i < 4; ++i)
    tile[ty + i*8][tx] = W[(size_t)(kb + ty + i*8) * Dsz + nb + tx];
  __syncthreads();
#pragma unroll
  for (int i = 0; i < 4; ++i)
    WT[(size_t)(nb + ty + i*8) * Dsz + kb + tx] = f2bf(tile[tx][ty + i*8]);
}

// ---------------- 128x128 bf16 MFMA GEMM: C = A(MxK) * BT(NxK)^T ----------------
// z==0 gets scale0 (Q: 1/sqrt(64)*log2e). z==2 writes V transposed: VT[b][h][d][t].
template <bool F32OUT>
__global__ __launch_bounds__(256) void gemm128(const bfu* __restrict__ A, const bfu* __restrict__ Bt0,
                                               void* __restrict__ C0, int K, int N,
                                               size_t strideB, size_t strideC, float scale0) {
  const int tid = threadIdx.x, wave = tid >> 6, lane = tid & 63;
  const int g = lane >> 4, c = lane & 15;
  const int m0 = blockIdx.y * 128, n0 = blockIdx.x * 128;
  const bfu* Bt = Bt0 + strideB * blockIdx.z;
  const float scale = (blockIdx.z == 0) ? scale0 : 1.0f;
  __shared__ bfu As[128 * 32];
  __shared__ bfu Bs[128 * 32];
  floatx4 acc[4][4] = {};
  const int srow = lane >> 2, scol = (lane & 3) * 8;
  const bfu* gA = A  + (size_t)(m0 + srow) * K + scol;
  const bfu* gB = Bt + (size_t)(n0 + srow) * K + scol;
  const int wm = (wave >> 1) * 64, wn = (wave & 1) * 64;
  for (int k0 = 0; k0 < K; k0 += 32) {
    __syncthreads();
#pragma unroll
    for (int cc = 0; cc < 2; ++cc) {
      const int chunk = wave * 2 + cc;
      async16(gA + (size_t)chunk * 16 * K + k0, &As[chunk * 512]);
      async16(gB + (size_t)chunk * 16 * K + k0, &Bs[chunk * 512]);
    }
    __syncthreads();
    short8 afr[4], bfr[4];
#pragma unroll
    for (int t = 0; t < 4; ++t) afr[t] = *(const short8*)&As[(wm + t*16 + c) * 32 + g * 8];
#pragma unroll
    for (int t = 0; t < 4; ++t) bfr[t] = *(const short8*)&Bs[(wn + t*16 + c) * 32 + g * 8];
#pragma unroll
    for (int i = 0; i < 4; ++i)
#pragma unroll
      for (int j = 0; j < 4; ++j)
        acc[i][j] = __builtin_amdgcn_mfma_f32_16x16x32_bf16(afr[i], bfr[j], acc[i][j], 0, 0, 0);
  }
  const bool vtrans = (!F32OUT) && (blockIdx.z == 2);
#pragma unroll
  for (int i = 0; i < 4; ++i) {
#pragma unroll
    for (int j = 0; j < 4; ++j) {
      const int m = m0 + wm + i*16 + g*4;
      const int n = n0 + wn + j*16 + c;
      if (vtrans) {
        // VT[((b*16+h)*64 + d)*2048 + t], 4 consecutive t -> b64 store
        bfu* vtp = (bfu*)C0 + (size_t)2 * strideC;
        size_t o = ((size_t)((m >> 11) * 16 + (n >> 6)) * 64 + (n & 63)) * Tsz + (m & 2047);
        short4v pk;
#pragma unroll
        for (int r = 0; r < 4; ++r) pk[r] = (short)f2bf(acc[i][j][r]);
        *(short4v*)&vtp[o] = pk;
      } else {
#pragma unroll
        for (int r = 0; r < 4; ++r) {
          float v = acc[i][j][r] * scale;
          if (F32OUT) ((float*)C0)[(size_t)(m + r) * N + n] = v;
          else        ((bfu*)C0)[strideC * blockIdx.z + (size_t)(m + r) * N + n] = f2bf(v);
        }
      }
    }
  }
}

// ---------------- causal flash attention (S^T formulation) ----------------
// Q,K in qkv natural [b*T+t][h*64+d]; V transposed at qkv+2*M*D as VT[b][h][d][t].
// Q pre-scaled by log2e/sqrt(DH). grid (16, 32): block handles q-tiles {p, 31-p} of
// 64 rows; 4 waves x 16 q-rows each; 128-key tiles; XOR-swizzled LDS, async staging.
__global__ __launch_bounds__(256, 2) void attn_kernel(const bfu* __restrict__ qkv,
                                                      bfu* __restrict__ obuf) {
  const int tid = threadIdx.x, wave = tid >> 6, lane = tid & 63;
  const int g = (lane >> 4) & 3, c = lane & 15, c7 = c & 7;
  const int bh = blockIdx.y, b = bh >> 4, h = bh & 15;
  const size_t hb = (size_t)b * Tsz * Dsz + h * 64;
  const bfu* Qp = qkv + hb;
  const bfu* Kp = qkv + (size_t)Msz * Dsz + hb;
  const bfu* Vt = qkv + (size_t)2 * Msz * Dsz + (size_t)bh * 64 * Tsz;

  __shared__ bfu Ks[128 * 64];      // [key][d], d-granules XOR key&7
  __shared__ bfu Vs[64 * 128];      // [d][key], key-granules XOR d&7
  __shared__ bfu Ps[4][16 * 128];   // per-wave [q][key], key-granules XOR q&7

  const int kst_row = lane >> 3;                    // K staging: 8 lanes/key-row
  const int kst_off = ((lane & 7) ^ kst_row) << 3;
  const int vst_row = lane >> 4;                    // V staging: 16 lanes/d-row

  for (int half = 0; half < 2; ++half) {
    const int j = half ? (31 - (int)blockIdx.x) : (int)blockIdx.x;
    const int qw = j * 64 + wave * 16;
    const int ktm = j >> 1;

    short8 bq[2];                    // Q B-frags: n=q=qw+c, k=d
#pragma unroll
    for (int kk = 0; kk < 2; ++kk)
      bq[kk] = *(const short8*)(Qp + (size_t)(qw + c) * Dsz + kk * 32 + g * 8);

    floatx4 acc[4] = {};             // O: rows q=4g+r, cols d=nd*16+c
    float mi = -3.0e38f, li = 0.0f;  // state for q = qw + c (replicated over g)

    for (int kt = 0; kt <= ktm; ++kt) {
      __syncthreads();
#pragma unroll
      for (int cc = 0; cc < 4; ++cc) {     // stage 4 K-chunks + 4 V-chunks per wave
        const int ch = wave * 4 + cc;
        async16(Kp + (size_t)(kt * 128 + ch * 8 + kst_row) * Dsz + kst_off, &Ks[ch * 512]);
        const int drow = ch * 4 + vst_row;
        async16(Vt + (size_t)drow * Tsz + kt * 128 + (((lane & 15) ^ (drow & 7)) << 3), &Vs[ch * 512]);
      }
      __syncthreads();

      // S^T[key][q] = K * Q^T
      floatx4 st[8] = {};
#pragma unroll
      for (int kk = 0; kk < 2; ++kk)
#pragma unroll
        for (int mk = 0; mk < 8; ++mk) {
          const short8 kf = *(const short8*)&Ks[(mk * 16 + c) * 64 + (((kk * 4 + g) ^ c7) << 3)];
          st[mk] = __builtin_amdgcn_mfma_f32_16x16x32_bf16(kf, bq[kk], st[mk], 0, 0, 0);
        }

      if (kt == ktm) {                 // causal mask (diagonal tile only)
#pragma unroll
        for (int mk = 0; mk < 8; ++mk) {
          const int keyb = kt * 128 + mk * 16 + g * 4;
#pragma unroll
          for (int r = 0; r < 4; ++r)
            if (keyb + r > qw + c) st[mk][r] = -1.0e38f;
        }
      }

      // online softmax over this tile's 128 keys (per lane: q = qw+c)
      float mloc = -3.0e38f;
#pragma unroll
      for (int mk = 0; mk < 8; ++mk)
#pragma unroll
        for (int r = 0; r < 4; ++r) mloc = fmaxf(mloc, st[mk][r]);
      mloc = fmaxf(mloc, __shfl_xor(mloc, 16));
      mloc = fmaxf(mloc, __shfl_xor(mloc, 32));
      const float mnew = fmaxf(mi, mloc);
      const float alpha = exp2f(mi - mnew);
      mi = mnew;
      float sum = 0.0f;
#pragma unroll
      for (int mk = 0; mk < 8; ++mk) {
        short4v pk;
#pragma unroll
        for (int r = 0; r < 4; ++r) {
          const float p = exp2f(st[mk][r] - mnew);
          sum += p;
          pk[r] = (short)f2bf(p);
        }
        *(short4v*)&Ps[wave][c * 128 + (((mk * 2 + (g >> 1)) ^ c7) << 3) + ((g & 1) << 2)] = pk;
      }
      sum += __shfl_xor(sum, 16);
      sum += __shfl_xor(sum, 32);
      li = li * alpha + sum;

      float al[4];
#pragma unroll
      for (int r = 0; r < 4; ++r) al[r] = __shfl(alpha, (lane & 48) | (g * 4 + r));
#pragma unroll
      for (int nd = 0; nd < 4; ++nd)
#pragma unroll
        for (int r = 0; r < 4; ++r) acc[nd][r] *= al[r];

      // O += P * V
#pragma unroll
      for (int kc = 0; kc < 4; ++kc) {
        const int sl = ((kc * 4 + g) ^ c7) << 3;
        const short8 pf = *(const short8*)&Ps[wave][c * 128 + sl];
#pragma unroll
        for (int nd = 0; nd < 4; ++nd) {
          const short8 vf = *(const short8*)&Vs[(nd * 16 + c) * 128 + sl];
          acc[nd] = __builtin_amdgcn_mfma_f32_16x16x32_bf16(pf, vf, acc[nd], 0, 0, 0);
        }
      }
    }

    // epilogue: O / l
    float inv[4];
#pragma unroll
    for (int r = 0; r < 4; ++r) inv[r] = 1.0f / __shfl(li, (lane & 48) | (g * 4 + r));
#pragma unroll
    for (int nd = 0; nd < 4; ++nd)
#pragma unroll
      for (int r = 0; r < 4; ++r)
        obuf[(size_t)(b * Tsz + qw + g * 4 + r) * Dsz + h * 64 + nd * 16 + c] =
            f2bf(acc[nd][r] * inv[r]);
  }
}

extern "C" void kernel_launch(void* const* d_in, const int* in_sizes, int n_in,
                              void* d_out, int out_size, void* d_ws, size_t ws_size,
                              hipStream_t stream) {
  const float* x  = (const float*)d_in[0];
  const float* Wq = (const float*)d_in[1];
  const float* Wk = (const float*)d_in[2];
  const float* Wv = (const float*)d_in[3];
  const float* Wo = (const float*)d_in[4];
  float* out = (float*)d_out;

  // workspace (bf16 elems): xb 4M | wt 4x1M | qkv 3x4M (Q,K natural; slot 2 = VT) | obuf 4M
  bfu* xb   = (bfu*)d_ws;
  bfu* wt   = xb  + (size_t)Msz * Dsz;
  bfu* qkv  = wt  + (size_t)4 * Dsz * Dsz;
  bfu* obuf = qkv + (size_t)3 * Msz * Dsz;

  convert_x<<<dim3(Msz * Dsz / (256 * 4)), dim3(256), 0, stream>>>(x, xb);
  transpose_w<<<dim3(32, 32, 4), dim3(32, 8), 0, stream>>>(Wq, Wk, Wv, Wo, wt);
  // QKV projections; Q scaled by log2(e)/sqrt(64); V written transposed (z==2)
  gemm128<false><<<dim3(Dsz / 128, Msz / 128, 3), dim3(256), 0, stream>>>(
      xb, wt, (void*)qkv, Dsz, Dsz, (size_t)Dsz * Dsz, (size_t)Msz * Dsz,
      0.125f * 1.44269504088896f);
  attn_kernel<<<dim3(16, Bsz * NHsz), dim3(256), 0, stream>>>(qkv, obuf);
  // output projection -> fp32 d_out
  gemm128<true><<<dim3(Dsz / 128, Msz / 128, 1), dim3(256), 0, stream>>>(
      obuf, wt + (size_t)3 * Dsz * Dsz, (void*)out, Dsz, Dsz, (size_t)0, (size_t)0, 1.0f);
}